// Round 13
// baseline (326.587 us; speedup 1.0000x reference)
//
#include <hip/hip_runtime.h>

// WaterLevelGCN r13: r9-proven kernels, disjoint 40MB layout (ws=256MiB),
// single-call w1 (N=2048) + single non-atomic w2 (K=2048, f32+bias).
// LESSON (r10-r12): kernels with 48KB static LDS silently never ran; keep
// every kernel <= 44KB LDS. No buffer aliasing anywhere in this layout.
// Layout (bytes): qkQK@0(2M) Vg@2M(1M) Oacc@3M(2M) Lacc@5242880 counts@5308416
// cursor@5324800 offs@5341184 csr@5357572 dinv@5881860 dflag@5898244
// y_f32@6291456(2M) y_bf@8388608(1M) ao@9437184(2M) z@11534336(1M)
// az@12582912(1M) h1@13631488(2M) ah1@15728640(2M) h2@17825792(2M)
// t3@19922944(.5M) ff1@20971520(16M) ff2@37748736(2M)

typedef unsigned short u16;
typedef __attribute__((ext_vector_type(8))) short bf16x8;
typedef __attribute__((ext_vector_type(4))) float f32x4;

__device__ __forceinline__ float b2f(u16 u) {
  union { unsigned int i; float f; } x; x.i = ((unsigned int)u) << 16; return x.f;
}
__device__ __forceinline__ u16 f2b(float f) {
  union { float f; unsigned int i; } x; x.f = f;
  unsigned int r = x.i + 0x7FFFu + ((x.i >> 16) & 1u);
  return (u16)(r >> 16);
}
__device__ __forceinline__ float ld1(const void* p, size_t i, int bf) {
  return bf ? b2f(((const u16*)p)[i]) : ((const float*)p)[i];
}

// ---------------- dtype detect (insurance; proven bf16) ----------------
__global__ void detect_dtype(const void* x, int* flag) {
  __shared__ int cnt;
  if (threadIdx.x == 0) cnt = 0;
  __syncthreads();
  const u16* p = (const u16*)x;
  int c = 0;
  for (int i = threadIdx.x; i < 4096; i += 256) {
    int e = (p[i] >> 7) & 0xFF;
    if (e >= 140) c++;
  }
  atomicAdd(&cnt, c);
  __syncthreads();
  if (threadIdx.x == 0) flag[0] = (cnt < 64) ? 1 : 0;
}

// ------------- GEMM: C[.,N] = A[M,K]@B[N,K]^T, bf16 MFMA, 64x64 tile -------
// BK=128 staging, XOR-swizzled LDS (proven r9). 32 KB LDS.
// flags: 1=relu, 2=acc, 4=C f32, 8=bias, 16=A raw input, 32=atomic f32 acc,
//        64=A f32 internal (divL per-head normalize), 128=in_proj special.
__global__ __launch_bounds__(256) void gemm_mfma(
    const void* __restrict__ A, const void* __restrict__ B,
    const void* __restrict__ bias, void* __restrict__ C, void* __restrict__ C2,
    int N, int K, int lda, int ldb, int bRow0, int bK0, int flags,
    const int* __restrict__ dflag, const float* __restrict__ divL)
{
  const int wbf = *dflag;
  const int abf = (flags & 64) ? 0 : ((flags & 16) ? wbf : 1);
  __shared__ u16 As[64][128];
  __shared__ u16 Bs[64][128];
  const int tid = threadIdx.x;
  const int wv = tid >> 6, l = tid & 63;
  const int lr = l & 15, lq = l >> 4;
  const int row0 = blockIdx.y * 64, col0 = blockIdx.x * 64;
  const int qr = 32 * (wv >> 1), qc = 32 * (wv & 1);
  const int sr = tid >> 2, sb = tid & 3;
  const int Kz = K / gridDim.z;
  const int k0 = blockIdx.z * Kz;
  f32x4 acc[2][2] = {};
  for (int kt = k0; kt < k0 + Kz; kt += 128) {
    __syncthreads();
#pragma unroll
    for (int g = 0; g < 4; g++) {
      int b = sb + 4 * g;
      int cc = b * 8;
      int bs = (b ^ (sr & 15)) * 8;
      size_t offA = (size_t)(row0 + sr) * lda + kt + cc;
      if (abf) {
        *(bf16x8*)&As[sr][bs] = *(const bf16x8*)((const u16*)A + offA);
      } else {
        const float* pf = (const float*)A + offA;
        float iv = divL
            ? 1.0f / divL[(size_t)((kt + cc) >> 5) * 4096 + row0 + sr]
            : 1.0f;
        float4 f0 = *(const float4*)pf, f1 = *(const float4*)(pf + 4);
        u16 t[8] = {f2b(f0.x*iv), f2b(f0.y*iv), f2b(f0.z*iv), f2b(f0.w*iv),
                    f2b(f1.x*iv), f2b(f1.y*iv), f2b(f1.z*iv), f2b(f1.w*iv)};
        *(bf16x8*)&As[sr][bs] = *(bf16x8*)t;
      }
      size_t offB = (size_t)(bRow0 + col0 + sr) * ldb + bK0 + kt + cc;
      if (wbf) {
        *(bf16x8*)&Bs[sr][bs] = *(const bf16x8*)((const u16*)B + offB);
      } else {
        const float* pf = (const float*)B + offB;
        float4 f0 = *(const float4*)pf, f1 = *(const float4*)(pf + 4);
        u16 t[8] = {f2b(f0.x), f2b(f0.y), f2b(f0.z), f2b(f0.w),
                    f2b(f1.x), f2b(f1.y), f2b(f1.z), f2b(f1.w)};
        *(bf16x8*)&Bs[sr][bs] = *(bf16x8*)t;
      }
    }
    __syncthreads();
#pragma unroll
    for (int kk = 0; kk < 4; kk++) {
      int bx = ((4 * kk + lq) ^ lr) * 8;
      bf16x8 a0 = *(const bf16x8*)&As[qr + lr][bx];
      bf16x8 a1 = *(const bf16x8*)&As[qr + 16 + lr][bx];
      bf16x8 b0 = *(const bf16x8*)&Bs[qc + lr][bx];
      bf16x8 b1 = *(const bf16x8*)&Bs[qc + 16 + lr][bx];
      acc[0][0] = __builtin_amdgcn_mfma_f32_16x16x32_bf16(a0, b0, acc[0][0], 0, 0, 0);
      acc[0][1] = __builtin_amdgcn_mfma_f32_16x16x32_bf16(a0, b1, acc[0][1], 0, 0, 0);
      acc[1][0] = __builtin_amdgcn_mfma_f32_16x16x32_bf16(a1, b0, acc[1][0], 0, 0, 0);
      acc[1][1] = __builtin_amdgcn_mfma_f32_16x16x32_bf16(a1, b1, acc[1][1], 0, 0, 0);
    }
  }
  if ((flags & 128) && col0 >= 256) {
#pragma unroll
    for (int i = 0; i < 2; i++) {
#pragma unroll
      for (int j = 0; j < 2; j++) {
        int colg = col0 + qc + 16 * j + lr;
        int d = colg - 256;
        int rowbase = row0 + qr + 16 * i + lq * 4;
        float bb = ld1(bias, colg, wbf);
        ushort4 pv = make_ushort4(
            f2b(acc[i][j][0] + bb), f2b(acc[i][j][1] + bb),
            f2b(acc[i][j][2] + bb), f2b(acc[i][j][3] + bb));
        *(ushort4*)((u16*)C2 + (size_t)d * 4096 + rowbase) = pv;
      }
    }
    return;
  }
  const int ldc = (flags & 128) ? 256 : N;
#pragma unroll
  for (int i = 0; i < 2; i++) {
#pragma unroll
    for (int j = 0; j < 2; j++) {
#pragma unroll
      for (int r = 0; r < 4; r++) {
        int row = row0 + qr + 16 * i + lq * 4 + r;
        int col = col0 + qc + 16 * j + lr;
        float v = acc[i][j][r];
        if (flags & 8) v += ld1(bias, bRow0 + col, wbf);
        if (flags & 1) v = fmaxf(v, 0.f);
        size_t idx = (size_t)row * ldc + col;
        if (flags & 32) {
          atomicAdd(&((float*)C)[idx], v);
        } else if (flags & 4) {
          float* Cf = (float*)C;
          if (flags & 2) v += Cf[idx];
          Cf[idx] = v;
        } else {
          ((u16*)C)[idx] = f2b(v);
        }
      }
    }
  }
}

// ------ split-K flash attention, fixed-shift softmax (proven r9) -----------
__global__ __launch_bounds__(256) void attn_part(
    const u16* __restrict__ qk, const u16* __restrict__ Vg,
    float* __restrict__ O, float* __restrict__ L)
{
  const int qt = blockIdx.x, h = blockIdx.y, kc = blockIdx.z;
  const int n0 = qt * 64;
  __shared__ u16 Qs[64][32];
  __shared__ u16 Ks[64][32];
  __shared__ u16 Vt[32][64];
  __shared__ u16 Ps[64][64];
  const int tid = threadIdx.x;
  const int wv = tid >> 6, l = tid & 63;
  const int lr = l & 15, lq = l >> 4;
  const int sr = tid >> 2, sb = tid & 3;
  const int vr = tid >> 3, vb = tid & 7;
  *(bf16x8*)&Qs[sr][(sb ^ (sr & 3)) * 8] =
      *(const bf16x8*)(qk + (size_t)(n0 + sr) * 256 + h * 32 + sb * 8);
  __syncthreads();
  const float sc = 0.17677669529663687f;  // 1/sqrt(32), folded into Q frag
  bf16x8 qf;
  {
    bf16x8 qraw = *(const bf16x8*)&Qs[16 * wv + lr][(lq ^ (lr & 3)) * 8];
#pragma unroll
    for (int t = 0; t < 8; t++)
      qf[t] = (short)f2b(b2f((u16)qraw[t]) * sc);
  }
  f32x4 o0 = {}, o1 = {};
  float psum[4] = {0.f, 0.f, 0.f, 0.f};
  for (int t = 0; t < 16; t++) {
    const int m0 = kc * 1024 + t * 64;
    __syncthreads();
    *(bf16x8*)&Ks[sr][(sb ^ (sr & 3)) * 8] =
        *(const bf16x8*)(qk + (size_t)(m0 + sr) * 256 + 128 + h * 32 + sb * 8);
    *(bf16x8*)&Vt[vr][(vb ^ (vr & 7)) * 8] =
        *(const bf16x8*)(Vg + (size_t)(h * 32 + vr) * 4096 + m0 + vb * 8);
    __syncthreads();
    f32x4 s[4];
#pragma unroll
    for (int jt = 0; jt < 4; jt++) {
      bf16x8 kf = *(const bf16x8*)&Ks[16 * jt + lr][(lq ^ (lr & 3)) * 8];
      f32x4 z = {};
      s[jt] = __builtin_amdgcn_mfma_f32_16x16x32_bf16(qf, kf, z, 0, 0, 0);
    }
#pragma unroll
    for (int jt = 0; jt < 4; jt++)
#pragma unroll
      for (int r = 0; r < 4; r++) {
        float p = __expf(s[jt][r]);
        psum[r] += p;
        int qrow = 16 * wv + lq * 4 + r;
        int bb = (2 * jt + (lr >> 3)) ^ (qrow & 7);
        Ps[qrow][bb * 8 + (lr & 7)] = f2b(p);
      }
    __syncthreads();
#pragma unroll
    for (int c = 0; c < 2; c++) {
      int bx = ((4 * c + lq) ^ (lr & 7)) * 8;
      bf16x8 pf = *(const bf16x8*)&Ps[16 * wv + lr][bx];
      bf16x8 v0 = *(const bf16x8*)&Vt[lr][bx];
      bf16x8 v1 = *(const bf16x8*)&Vt[16 + lr][bx];
      o0 = __builtin_amdgcn_mfma_f32_16x16x32_bf16(pf, v0, o0, 0, 0, 0);
      o1 = __builtin_amdgcn_mfma_f32_16x16x32_bf16(pf, v1, o1, 0, 0, 0);
    }
  }
#pragma unroll
  for (int r = 0; r < 4; r++) {
    int row = n0 + 16 * wv + lq * 4 + r;
    atomicAdd(&O[(size_t)row * 128 + h * 32 + lr],      o0[r]);
    atomicAdd(&O[(size_t)row * 128 + h * 32 + 16 + lr], o1[r]);
    float ps = psum[r];
    ps += __shfl_xor(ps, 1); ps += __shfl_xor(ps, 2);
    ps += __shfl_xor(ps, 4); ps += __shfl_xor(ps, 8);
    if (lr == 0) atomicAdd(&L[h * 4096 + row], ps);
  }
}

// ------- LayerNorm(A + R (+ rbias[col]))*g + b (proven r9) -----------------
__global__ __launch_bounds__(256) void ln_res(
    const void* __restrict__ A, int a_mode, const float* __restrict__ R,
    const void* __restrict__ rbias,
    const void* __restrict__ g, const void* __restrict__ b,
    u16* __restrict__ out_bf, float* __restrict__ out_f32,
    const int* __restrict__ dflag)
{
  const int wbf = *dflag;
  const int abf = a_mode ? wbf : 0;
  int row = blockIdx.x * 4 + (threadIdx.x >> 6);
  int lane = threadIdx.x & 63;
  size_t i0 = (size_t)row * 128 + lane, i1 = i0 + 64;
  float v0 = ld1(A, i0, abf) + R[i0];
  float v1 = ld1(A, i1, abf) + R[i1];
  if (rbias) { v0 += ld1(rbias, lane, wbf); v1 += ld1(rbias, lane + 64, wbf); }
  float s = v0 + v1, sq = v0 * v0 + v1 * v1;
  for (int off = 32; off; off >>= 1) { s += __shfl_down(s, off); sq += __shfl_down(sq, off); }
  s = __shfl(s, 0); sq = __shfl(sq, 0);
  float mu = s * (1.f / 128.f);
  float var = sq * (1.f / 128.f) - mu * mu;
  float rs = rsqrtf(var + 1e-5f);
  float r0 = (v0 - mu) * rs * ld1(g, lane, wbf) + ld1(b, lane, wbf);
  float r1 = (v1 - mu) * rs * ld1(g, lane + 64, wbf) + ld1(b, lane + 64, wbf);
  out_bf[i0] = f2b(r0);
  out_bf[i1] = f2b(r1);
  if (out_f32) { out_f32[i0] = r0; out_f32[i1] = r1; }
}

// ---------------- degree / CSR build (proven r9) ----------------
__global__ void count_deg(const int* __restrict__ dst, int* __restrict__ counts, int E) {
  int e = blockIdx.x * 256 + threadIdx.x;
  if (e < E) atomicAdd(&counts[dst[e]], 1);
}

__global__ __launch_bounds__(1024) void scan4096(
    const int* __restrict__ counts, int* __restrict__ offs,
    float* __restrict__ dinv)
{
  __shared__ int buf[4096];
  __shared__ int part[1024];
  int t = threadIdx.x;
  for (int i = t; i < 4096; i += 1024) buf[i] = counts[i];
  __syncthreads();
  int base = t * 4;
  int s = buf[base] + buf[base + 1] + buf[base + 2] + buf[base + 3];
  part[t] = s;
  __syncthreads();
  for (int off = 1; off < 1024; off <<= 1) {
    int v = (t >= off) ? part[t - off] : 0;
    __syncthreads();
    part[t] += v;
    __syncthreads();
  }
  int run = (t == 0) ? 0 : part[t - 1];
  for (int j = 0; j < 4; j++) {
    int c = buf[base + j];
    offs[base + j] = run;
    dinv[base + j] = rsqrtf((float)(c + 1));
    run += c;
  }
  if (t == 1023) offs[4096] = run;
}

__global__ void fill_csr(const int* __restrict__ src, const int* __restrict__ dst,
                         const int* __restrict__ offs, int* __restrict__ cursor,
                         int* __restrict__ csr, int E) {
  int e = blockIdx.x * 256 + threadIdx.x;
  if (e < E) {
    int t = dst[e];
    int pos = offs[t] + atomicAdd(&cursor[t], 1);
    csr[pos] = src[e];
  }
}

// -------- GCN gather, ushort4-vectorized (proven r9) -----------------------
__global__ __launch_bounds__(256) void gcn_gather(
    const u16* __restrict__ h, const float* __restrict__ dinv,
    const int* __restrict__ offs, const int* __restrict__ csr,
    const void* __restrict__ bias, void* __restrict__ out,
    int F, int relu, int final_out, const int* __restrict__ dflag)
{
  const int wbf = *dflag;
  const int tpn = F >> 2;
  const int node = blockIdx.x * (256 / tpn) + threadIdx.x / tpn;
  const int f = (threadIdx.x % tpn) * 4;
  float di = dinv[node];
  ushort4 hv = *(const ushort4*)(h + (size_t)node * F + f);
  float a0 = di * b2f(hv.x), a1 = di * b2f(hv.y);
  float a2 = di * b2f(hv.z), a3 = di * b2f(hv.w);
  int e0 = offs[node], e1 = offs[node + 1];
  for (int e = e0; e < e1; e++) {
    int s = csr[e];
    float ds = dinv[s];
    ushort4 sv = *(const ushort4*)(h + (size_t)s * F + f);
    a0 += ds * b2f(sv.x); a1 += ds * b2f(sv.y);
    a2 += ds * b2f(sv.z); a3 += ds * b2f(sv.w);
  }
  float b0 = bias ? ld1(bias, f, wbf)     : 0.f;
  float b1 = bias ? ld1(bias, f + 1, wbf) : 0.f;
  float b2 = bias ? ld1(bias, f + 2, wbf) : 0.f;
  float b3 = bias ? ld1(bias, f + 3, wbf) : 0.f;
  float v0 = a0 * di + b0, v1 = a1 * di + b1;
  float v2 = a2 * di + b2, v3 = a3 * di + b3;
  if (relu) {
    v0 = fmaxf(v0, 0.f); v1 = fmaxf(v1, 0.f);
    v2 = fmaxf(v2, 0.f); v3 = fmaxf(v3, 0.f);
  }
  size_t idx = (size_t)node * F + f;
  if (!final_out || wbf) {
    *(ushort4*)((u16*)out + idx) = make_ushort4(f2b(v0), f2b(v1), f2b(v2), f2b(v3));
  } else {
    *(float4*)((float*)out + idx) = make_float4(v0, v1, v2, v3);
  }
}

extern "C" void kernel_launch(void* const* d_in, const int* in_sizes, int n_in,
                              void* d_out, int out_size, void* d_ws, size_t ws_size,
                              hipStream_t stream)
{
  const void* x          = d_in[0];
  const int*  edge       = (const int*)d_in[1];
  const void* in_proj_w  = d_in[2];
  const void* in_proj_b  = d_in[3];
  const void* out_proj_w = d_in[4];
  const void* out_proj_b = d_in[5];
  const void* ln1_g      = d_in[6];
  const void* ln1_b      = d_in[7];
  const void* ffn_w1     = d_in[8];
  const void* ffn_b1     = d_in[9];
  const void* ffn_w2     = d_in[10];
  const void* ffn_b2     = d_in[11];
  const void* ln2_g      = d_in[12];
  const void* ln2_b      = d_in[13];
  const void* g1w        = d_in[14];
  const void* g1b        = d_in[15];
  const void* g2w        = d_in[16];
  const void* g2b        = d_in[17];
  const void* g3w        = d_in[18];
  const void* g3b        = d_in[19];
  const int E = in_sizes[1] / 2;
  const int* esrc = edge;
  const int* edst = edge + E;

  char* wsb     = (char*)d_ws;
  // fully disjoint layout (ws = 256 MiB)
  u16*   qkQK   = (u16*)(wsb + 0);          // 2 MB
  u16*   Vg     = (u16*)(wsb + 2097152);    // 1 MB
  float* Oacc   = (float*)(wsb + 3145728);  // 2 MB
  float* Lacc   = (float*)(wsb + 5242880);  // 64 KB
  int*   counts = (int*)(wsb + 5308416);
  int*   cursor = (int*)(wsb + 5324800);
  int*   offs   = (int*)(wsb + 5341184);
  int*   csr    = (int*)(wsb + 5357572);
  float* dinv   = (float*)(wsb + 5881860);
  int*   dflag  = (int*)(wsb + 5898244);
  float* y_f32  = (float*)(wsb + 6291456);  // 2 MB
  u16*   y_bf   = (u16*)(wsb + 8388608);    // 1 MB
  float* ao     = (float*)(wsb + 9437184);  // 2 MB
  u16*   z_bf   = (u16*)(wsb + 11534336);   // 1 MB
  u16*   az     = (u16*)(wsb + 12582912);   // 1 MB
  u16*   h1     = (u16*)(wsb + 13631488);   // 2 MB
  u16*   ah1    = (u16*)(wsb + 15728640);   // 2 MB
  u16*   h2     = (u16*)(wsb + 17825792);   // 2 MB
  u16*   t3     = (u16*)(wsb + 19922944);   // 512 KB
  u16*   ff1    = (u16*)(wsb + 20971520);   // 16 MB [4096][2048]
  float* ff2    = (float*)(wsb + 37748736); // 2 MB

  detect_dtype<<<1, 256, 0, stream>>>(x, dflag);
  // zero Oacc, Lacc, counts, cursor in one shot (proven r9)
  hipMemsetAsync(wsb + 3145728, 0, 2195456, stream);

  // degree + CSR (shared by all 3 GCN layers)
  count_deg<<<(E + 255) / 256, 256, 0, stream>>>(edst, counts, E);
  scan4096<<<1, 1024, 0, stream>>>(counts, offs, dinv);
  fill_csr<<<(E + 255) / 256, 256, 0, stream>>>(esrc, edst, offs, cursor, csr, E);

  // transformer encoder layer
  gemm_mfma<<<dim3(6, 64), 256, 0, stream>>>(x, in_proj_w, in_proj_b, qkQK, Vg,
      384, 128, 128, 128, 0, 0, /*bias+Araw+qkv*/ 8 | 16 | 128, dflag, nullptr);
  attn_part<<<dim3(64, 4, 4), 256, 0, stream>>>(qkQK, Vg, Oacc, Lacc);
  gemm_mfma<<<dim3(2, 64), 256, 0, stream>>>(Oacc, out_proj_w, out_proj_b, ao, nullptr,
      128, 128, 128, 128, 0, 0, /*f32out+bias+Af32*/ 4 | 8 | 64, dflag, Lacc);
  ln_res<<<1024, 256, 0, stream>>>(x, 1, ao, nullptr, ln1_g, ln1_b, y_bf, y_f32, dflag);
  // FFN: one w1 call (proven kernel, grid-only change), one non-atomic w2
  gemm_mfma<<<dim3(32, 64), 256, 0, stream>>>(y_bf, ffn_w1, ffn_b1, ff1, nullptr,
      2048, 128, 128, 128, 0, 0, /*relu+bias*/ 1 | 8, dflag, nullptr);
  gemm_mfma<<<dim3(2, 64), 256, 0, stream>>>(ff1, ffn_w2, ffn_b2, ff2, nullptr,
      128, 2048, 2048, 2048, 0, 0, /*f32out+bias*/ 4 | 8, dflag, nullptr);
  ln_res<<<1024, 256, 0, stream>>>(y_f32, 0, ff2, nullptr, ln2_g, ln2_b, z_bf, nullptr, dflag);

  // 3-layer GCN; aggregation commutes with the weight multiply
  gcn_gather<<<512, 256, 0, stream>>>(z_bf, dinv, offs, csr, nullptr, az, 128, 0, 0, dflag);
  gemm_mfma<<<dim3(4, 64), 256, 0, stream>>>(az, g1w, g1b, h1, nullptr,
      256, 128, 128, 128, 0, 0, /*relu+bias*/ 1 | 8, dflag, nullptr);
  gcn_gather<<<1024, 256, 0, stream>>>(h1, dinv, offs, csr, nullptr, ah1, 256, 0, 0, dflag);
  gemm_mfma<<<dim3(4, 64), 256, 0, stream>>>(ah1, g2w, g2b, h2, nullptr,
      256, 256, 256, 256, 0, 0, /*relu+bias*/ 1 | 8, dflag, nullptr);
  gemm_mfma<<<dim3(1, 64), 256, 0, stream>>>(h2, g3w, nullptr, t3, nullptr,
      64, 256, 256, 256, 0, 0, 0, dflag, nullptr);
  gcn_gather<<<256, 256, 0, stream>>>(t3, dinv, offs, csr, g3b, d_out, 64, 0, 1, dflag);
}

// Round 14
// 310.739 us; speedup vs baseline: 1.0510x; 1.0510x over previous
//
#include <hip/hip_runtime.h>

// WaterLevelGCN r14: r13 with w2 restored to z-split atomic (z=8, 1024 blocks)
// -- r13's single-call w2 was latency-starved (128 blocks, 5% occupancy,
// 57us, MfmaUtil 1.3%). ffn_b2 moves back to ln2's rbias (r9-proven).
// LESSON (r10-r12): 48KB-LDS kernels silently never ran; keep LDS <= 44KB.
// Fully disjoint layout (ws = 256 MiB), no aliasing:
// qkQK@0(2M) Vg@2M(1M) Oacc@3M(2M) Lacc@5242880 counts@5308416 cursor@5324800
// offs@5341184 csr@5357572 dinv@5881860 dflag@5898244 y_f32@6291456(2M)
// y_bf@8388608(1M) ao@9437184(2M) z@11534336(1M) az@12582912(1M)
// h1@13631488(2M) ah1@15728640(2M) h2@17825792(2M) t3@19922944(.5M)
// ff1@20971520(16M) ff2@37748736(2M)

typedef unsigned short u16;
typedef __attribute__((ext_vector_type(8))) short bf16x8;
typedef __attribute__((ext_vector_type(4))) float f32x4;

__device__ __forceinline__ float b2f(u16 u) {
  union { unsigned int i; float f; } x; x.i = ((unsigned int)u) << 16; return x.f;
}
__device__ __forceinline__ u16 f2b(float f) {
  union { float f; unsigned int i; } x; x.f = f;
  unsigned int r = x.i + 0x7FFFu + ((x.i >> 16) & 1u);
  return (u16)(r >> 16);
}
__device__ __forceinline__ float ld1(const void* p, size_t i, int bf) {
  return bf ? b2f(((const u16*)p)[i]) : ((const float*)p)[i];
}

// ---------------- dtype detect (insurance; proven bf16) ----------------
__global__ void detect_dtype(const void* x, int* flag) {
  __shared__ int cnt;
  if (threadIdx.x == 0) cnt = 0;
  __syncthreads();
  const u16* p = (const u16*)x;
  int c = 0;
  for (int i = threadIdx.x; i < 4096; i += 256) {
    int e = (p[i] >> 7) & 0xFF;
    if (e >= 140) c++;
  }
  atomicAdd(&cnt, c);
  __syncthreads();
  if (threadIdx.x == 0) flag[0] = (cnt < 64) ? 1 : 0;
}

// ------------- GEMM: C[.,N] = A[M,K]@B[N,K]^T, bf16 MFMA, 64x64 tile -------
// BK=128 staging, XOR-swizzled LDS (proven r9). 32 KB LDS.
// flags: 1=relu, 2=acc, 4=C f32, 8=bias, 16=A raw input, 32=atomic f32 acc,
//        64=A f32 internal (divL per-head normalize), 128=in_proj special.
__global__ __launch_bounds__(256) void gemm_mfma(
    const void* __restrict__ A, const void* __restrict__ B,
    const void* __restrict__ bias, void* __restrict__ C, void* __restrict__ C2,
    int N, int K, int lda, int ldb, int bRow0, int bK0, int flags,
    const int* __restrict__ dflag, const float* __restrict__ divL)
{
  const int wbf = *dflag;
  const int abf = (flags & 64) ? 0 : ((flags & 16) ? wbf : 1);
  __shared__ u16 As[64][128];
  __shared__ u16 Bs[64][128];
  const int tid = threadIdx.x;
  const int wv = tid >> 6, l = tid & 63;
  const int lr = l & 15, lq = l >> 4;
  const int row0 = blockIdx.y * 64, col0 = blockIdx.x * 64;
  const int qr = 32 * (wv >> 1), qc = 32 * (wv & 1);
  const int sr = tid >> 2, sb = tid & 3;
  const int Kz = K / gridDim.z;
  const int k0 = blockIdx.z * Kz;
  f32x4 acc[2][2] = {};
  for (int kt = k0; kt < k0 + Kz; kt += 128) {
    __syncthreads();
#pragma unroll
    for (int g = 0; g < 4; g++) {
      int b = sb + 4 * g;
      int cc = b * 8;
      int bs = (b ^ (sr & 15)) * 8;
      size_t offA = (size_t)(row0 + sr) * lda + kt + cc;
      if (abf) {
        *(bf16x8*)&As[sr][bs] = *(const bf16x8*)((const u16*)A + offA);
      } else {
        const float* pf = (const float*)A + offA;
        float iv = divL
            ? 1.0f / divL[(size_t)((kt + cc) >> 5) * 4096 + row0 + sr]
            : 1.0f;
        float4 f0 = *(const float4*)pf, f1 = *(const float4*)(pf + 4);
        u16 t[8] = {f2b(f0.x*iv), f2b(f0.y*iv), f2b(f0.z*iv), f2b(f0.w*iv),
                    f2b(f1.x*iv), f2b(f1.y*iv), f2b(f1.z*iv), f2b(f1.w*iv)};
        *(bf16x8*)&As[sr][bs] = *(bf16x8*)t;
      }
      size_t offB = (size_t)(bRow0 + col0 + sr) * ldb + bK0 + kt + cc;
      if (wbf) {
        *(bf16x8*)&Bs[sr][bs] = *(const bf16x8*)((const u16*)B + offB);
      } else {
        const float* pf = (const float*)B + offB;
        float4 f0 = *(const float4*)pf, f1 = *(const float4*)(pf + 4);
        u16 t[8] = {f2b(f0.x), f2b(f0.y), f2b(f0.z), f2b(f0.w),
                    f2b(f1.x), f2b(f1.y), f2b(f1.z), f2b(f1.w)};
        *(bf16x8*)&Bs[sr][bs] = *(bf16x8*)t;
      }
    }
    __syncthreads();
#pragma unroll
    for (int kk = 0; kk < 4; kk++) {
      int bx = ((4 * kk + lq) ^ lr) * 8;
      bf16x8 a0 = *(const bf16x8*)&As[qr + lr][bx];
      bf16x8 a1 = *(const bf16x8*)&As[qr + 16 + lr][bx];
      bf16x8 b0 = *(const bf16x8*)&Bs[qc + lr][bx];
      bf16x8 b1 = *(const bf16x8*)&Bs[qc + 16 + lr][bx];
      acc[0][0] = __builtin_amdgcn_mfma_f32_16x16x32_bf16(a0, b0, acc[0][0], 0, 0, 0);
      acc[0][1] = __builtin_amdgcn_mfma_f32_16x16x32_bf16(a0, b1, acc[0][1], 0, 0, 0);
      acc[1][0] = __builtin_amdgcn_mfma_f32_16x16x32_bf16(a1, b0, acc[1][0], 0, 0, 0);
      acc[1][1] = __builtin_amdgcn_mfma_f32_16x16x32_bf16(a1, b1, acc[1][1], 0, 0, 0);
    }
  }
  if ((flags & 128) && col0 >= 256) {
#pragma unroll
    for (int i = 0; i < 2; i++) {
#pragma unroll
      for (int j = 0; j < 2; j++) {
        int colg = col0 + qc + 16 * j + lr;
        int d = colg - 256;
        int rowbase = row0 + qr + 16 * i + lq * 4;
        float bb = ld1(bias, colg, wbf);
        ushort4 pv = make_ushort4(
            f2b(acc[i][j][0] + bb), f2b(acc[i][j][1] + bb),
            f2b(acc[i][j][2] + bb), f2b(acc[i][j][3] + bb));
        *(ushort4*)((u16*)C2 + (size_t)d * 4096 + rowbase) = pv;
      }
    }
    return;
  }
  const int ldc = (flags & 128) ? 256 : N;
#pragma unroll
  for (int i = 0; i < 2; i++) {
#pragma unroll
    for (int j = 0; j < 2; j++) {
#pragma unroll
      for (int r = 0; r < 4; r++) {
        int row = row0 + qr + 16 * i + lq * 4 + r;
        int col = col0 + qc + 16 * j + lr;
        float v = acc[i][j][r];
        if (flags & 8) v += ld1(bias, bRow0 + col, wbf);
        if (flags & 1) v = fmaxf(v, 0.f);
        size_t idx = (size_t)row * ldc + col;
        if (flags & 32) {
          atomicAdd(&((float*)C)[idx], v);
        } else if (flags & 4) {
          float* Cf = (float*)C;
          if (flags & 2) v += Cf[idx];
          Cf[idx] = v;
        } else {
          ((u16*)C)[idx] = f2b(v);
        }
      }
    }
  }
}

// ------ split-K flash attention, fixed-shift softmax (proven r9) -----------
__global__ __launch_bounds__(256) void attn_part(
    const u16* __restrict__ qk, const u16* __restrict__ Vg,
    float* __restrict__ O, float* __restrict__ L)
{
  const int qt = blockIdx.x, h = blockIdx.y, kc = blockIdx.z;
  const int n0 = qt * 64;
  __shared__ u16 Qs[64][32];
  __shared__ u16 Ks[64][32];
  __shared__ u16 Vt[32][64];
  __shared__ u16 Ps[64][64];
  const int tid = threadIdx.x;
  const int wv = tid >> 6, l = tid & 63;
  const int lr = l & 15, lq = l >> 4;
  const int sr = tid >> 2, sb = tid & 3;
  const int vr = tid >> 3, vb = tid & 7;
  *(bf16x8*)&Qs[sr][(sb ^ (sr & 3)) * 8] =
      *(const bf16x8*)(qk + (size_t)(n0 + sr) * 256 + h * 32 + sb * 8);
  __syncthreads();
  const float sc = 0.17677669529663687f;  // 1/sqrt(32), folded into Q frag
  bf16x8 qf;
  {
    bf16x8 qraw = *(const bf16x8*)&Qs[16 * wv + lr][(lq ^ (lr & 3)) * 8];
#pragma unroll
    for (int t = 0; t < 8; t++)
      qf[t] = (short)f2b(b2f((u16)qraw[t]) * sc);
  }
  f32x4 o0 = {}, o1 = {};
  float psum[4] = {0.f, 0.f, 0.f, 0.f};
  for (int t = 0; t < 16; t++) {
    const int m0 = kc * 1024 + t * 64;
    __syncthreads();
    *(bf16x8*)&Ks[sr][(sb ^ (sr & 3)) * 8] =
        *(const bf16x8*)(qk + (size_t)(m0 + sr) * 256 + 128 + h * 32 + sb * 8);
    *(bf16x8*)&Vt[vr][(vb ^ (vr & 7)) * 8] =
        *(const bf16x8*)(Vg + (size_t)(h * 32 + vr) * 4096 + m0 + vb * 8);
    __syncthreads();
    f32x4 s[4];
#pragma unroll
    for (int jt = 0; jt < 4; jt++) {
      bf16x8 kf = *(const bf16x8*)&Ks[16 * jt + lr][(lq ^ (lr & 3)) * 8];
      f32x4 z = {};
      s[jt] = __builtin_amdgcn_mfma_f32_16x16x32_bf16(qf, kf, z, 0, 0, 0);
    }
#pragma unroll
    for (int jt = 0; jt < 4; jt++)
#pragma unroll
      for (int r = 0; r < 4; r++) {
        float p = __expf(s[jt][r]);
        psum[r] += p;
        int qrow = 16 * wv + lq * 4 + r;
        int bb = (2 * jt + (lr >> 3)) ^ (qrow & 7);
        Ps[qrow][bb * 8 + (lr & 7)] = f2b(p);
      }
    __syncthreads();
#pragma unroll
    for (int c = 0; c < 2; c++) {
      int bx = ((4 * c + lq) ^ (lr & 7)) * 8;
      bf16x8 pf = *(const bf16x8*)&Ps[16 * wv + lr][bx];
      bf16x8 v0 = *(const bf16x8*)&Vt[lr][bx];
      bf16x8 v1 = *(const bf16x8*)&Vt[16 + lr][bx];
      o0 = __builtin_amdgcn_mfma_f32_16x16x32_bf16(pf, v0, o0, 0, 0, 0);
      o1 = __builtin_amdgcn_mfma_f32_16x16x32_bf16(pf, v1, o1, 0, 0, 0);
    }
  }
#pragma unroll
  for (int r = 0; r < 4; r++) {
    int row = n0 + 16 * wv + lq * 4 + r;
    atomicAdd(&O[(size_t)row * 128 + h * 32 + lr],      o0[r]);
    atomicAdd(&O[(size_t)row * 128 + h * 32 + 16 + lr], o1[r]);
    float ps = psum[r];
    ps += __shfl_xor(ps, 1); ps += __shfl_xor(ps, 2);
    ps += __shfl_xor(ps, 4); ps += __shfl_xor(ps, 8);
    if (lr == 0) atomicAdd(&L[h * 4096 + row], ps);
  }
}

// ------- LayerNorm(A + R (+ rbias[col]))*g + b (proven r9) -----------------
__global__ __launch_bounds__(256) void ln_res(
    const void* __restrict__ A, int a_mode, const float* __restrict__ R,
    const void* __restrict__ rbias,
    const void* __restrict__ g, const void* __restrict__ b,
    u16* __restrict__ out_bf, float* __restrict__ out_f32,
    const int* __restrict__ dflag)
{
  const int wbf = *dflag;
  const int abf = a_mode ? wbf : 0;
  int row = blockIdx.x * 4 + (threadIdx.x >> 6);
  int lane = threadIdx.x & 63;
  size_t i0 = (size_t)row * 128 + lane, i1 = i0 + 64;
  float v0 = ld1(A, i0, abf) + R[i0];
  float v1 = ld1(A, i1, abf) + R[i1];
  if (rbias) { v0 += ld1(rbias, lane, wbf); v1 += ld1(rbias, lane + 64, wbf); }
  float s = v0 + v1, sq = v0 * v0 + v1 * v1;
  for (int off = 32; off; off >>= 1) { s += __shfl_down(s, off); sq += __shfl_down(sq, off); }
  s = __shfl(s, 0); sq = __shfl(sq, 0);
  float mu = s * (1.f / 128.f);
  float var = sq * (1.f / 128.f) - mu * mu;
  float rs = rsqrtf(var + 1e-5f);
  float r0 = (v0 - mu) * rs * ld1(g, lane, wbf) + ld1(b, lane, wbf);
  float r1 = (v1 - mu) * rs * ld1(g, lane + 64, wbf) + ld1(b, lane + 64, wbf);
  out_bf[i0] = f2b(r0);
  out_bf[i1] = f2b(r1);
  if (out_f32) { out_f32[i0] = r0; out_f32[i1] = r1; }
}

// ---------------- degree / CSR build (proven r9) ----------------
__global__ void count_deg(const int* __restrict__ dst, int* __restrict__ counts, int E) {
  int e = blockIdx.x * 256 + threadIdx.x;
  if (e < E) atomicAdd(&counts[dst[e]], 1);
}

__global__ __launch_bounds__(1024) void scan4096(
    const int* __restrict__ counts, int* __restrict__ offs,
    float* __restrict__ dinv)
{
  __shared__ int buf[4096];
  __shared__ int part[1024];
  int t = threadIdx.x;
  for (int i = t; i < 4096; i += 1024) buf[i] = counts[i];
  __syncthreads();
  int base = t * 4;
  int s = buf[base] + buf[base + 1] + buf[base + 2] + buf[base + 3];
  part[t] = s;
  __syncthreads();
  for (int off = 1; off < 1024; off <<= 1) {
    int v = (t >= off) ? part[t - off] : 0;
    __syncthreads();
    part[t] += v;
    __syncthreads();
  }
  int run = (t == 0) ? 0 : part[t - 1];
  for (int j = 0; j < 4; j++) {
    int c = buf[base + j];
    offs[base + j] = run;
    dinv[base + j] = rsqrtf((float)(c + 1));
    run += c;
  }
  if (t == 1023) offs[4096] = run;
}

__global__ void fill_csr(const int* __restrict__ src, const int* __restrict__ dst,
                         const int* __restrict__ offs, int* __restrict__ cursor,
                         int* __restrict__ csr, int E) {
  int e = blockIdx.x * 256 + threadIdx.x;
  if (e < E) {
    int t = dst[e];
    int pos = offs[t] + atomicAdd(&cursor[t], 1);
    csr[pos] = src[e];
  }
}

// -------- GCN gather, ushort4-vectorized (proven r9) -----------------------
__global__ __launch_bounds__(256) void gcn_gather(
    const u16* __restrict__ h, const float* __restrict__ dinv,
    const int* __restrict__ offs, const int* __restrict__ csr,
    const void* __restrict__ bias, void* __restrict__ out,
    int F, int relu, int final_out, const int* __restrict__ dflag)
{
  const int wbf = *dflag;
  const int tpn = F >> 2;
  const int node = blockIdx.x * (256 / tpn) + threadIdx.x / tpn;
  const int f = (threadIdx.x % tpn) * 4;
  float di = dinv[node];
  ushort4 hv = *(const ushort4*)(h + (size_t)node * F + f);
  float a0 = di * b2f(hv.x), a1 = di * b2f(hv.y);
  float a2 = di * b2f(hv.z), a3 = di * b2f(hv.w);
  int e0 = offs[node], e1 = offs[node + 1];
  for (int e = e0; e < e1; e++) {
    int s = csr[e];
    float ds = dinv[s];
    ushort4 sv = *(const ushort4*)(h + (size_t)s * F + f);
    a0 += ds * b2f(sv.x); a1 += ds * b2f(sv.y);
    a2 += ds * b2f(sv.z); a3 += ds * b2f(sv.w);
  }
  float b0 = bias ? ld1(bias, f, wbf)     : 0.f;
  float b1 = bias ? ld1(bias, f + 1, wbf) : 0.f;
  float b2 = bias ? ld1(bias, f + 2, wbf) : 0.f;
  float b3 = bias ? ld1(bias, f + 3, wbf) : 0.f;
  float v0 = a0 * di + b0, v1 = a1 * di + b1;
  float v2 = a2 * di + b2, v3 = a3 * di + b3;
  if (relu) {
    v0 = fmaxf(v0, 0.f); v1 = fmaxf(v1, 0.f);
    v2 = fmaxf(v2, 0.f); v3 = fmaxf(v3, 0.f);
  }
  size_t idx = (size_t)node * F + f;
  if (!final_out || wbf) {
    *(ushort4*)((u16*)out + idx) = make_ushort4(f2b(v0), f2b(v1), f2b(v2), f2b(v3));
  } else {
    *(float4*)((float*)out + idx) = make_float4(v0, v1, v2, v3);
  }
}

extern "C" void kernel_launch(void* const* d_in, const int* in_sizes, int n_in,
                              void* d_out, int out_size, void* d_ws, size_t ws_size,
                              hipStream_t stream)
{
  const void* x          = d_in[0];
  const int*  edge       = (const int*)d_in[1];
  const void* in_proj_w  = d_in[2];
  const void* in_proj_b  = d_in[3];
  const void* out_proj_w = d_in[4];
  const void* out_proj_b = d_in[5];
  const void* ln1_g      = d_in[6];
  const void* ln1_b      = d_in[7];
  const void* ffn_w1     = d_in[8];
  const void* ffn_b1     = d_in[9];
  const void* ffn_w2     = d_in[10];
  const void* ffn_b2     = d_in[11];
  const void* ln2_g      = d_in[12];
  const void* ln2_b      = d_in[13];
  const void* g1w        = d_in[14];
  const void* g1b        = d_in[15];
  const void* g2w        = d_in[16];
  const void* g2b        = d_in[17];
  const void* g3w        = d_in[18];
  const void* g3b        = d_in[19];
  const int E = in_sizes[1] / 2;
  const int* esrc = edge;
  const int* edst = edge + E;

  char* wsb     = (char*)d_ws;
  // fully disjoint layout (ws = 256 MiB)
  u16*   qkQK   = (u16*)(wsb + 0);          // 2 MB
  u16*   Vg     = (u16*)(wsb + 2097152);    // 1 MB
  float* Oacc   = (float*)(wsb + 3145728);  // 2 MB
  float* Lacc   = (float*)(wsb + 5242880);  // 64 KB
  int*   counts = (int*)(wsb + 5308416);
  int*   cursor = (int*)(wsb + 5324800);
  int*   offs   = (int*)(wsb + 5341184);
  int*   csr    = (int*)(wsb + 5357572);
  float* dinv   = (float*)(wsb + 5881860);
  int*   dflag  = (int*)(wsb + 5898244);
  float* y_f32  = (float*)(wsb + 6291456);  // 2 MB
  u16*   y_bf   = (u16*)(wsb + 8388608);    // 1 MB
  float* ao     = (float*)(wsb + 9437184);  // 2 MB
  u16*   z_bf   = (u16*)(wsb + 11534336);   // 1 MB
  u16*   az     = (u16*)(wsb + 12582912);   // 1 MB
  u16*   h1     = (u16*)(wsb + 13631488);   // 2 MB
  u16*   ah1    = (u16*)(wsb + 15728640);   // 2 MB
  u16*   h2     = (u16*)(wsb + 17825792);   // 2 MB
  u16*   t3     = (u16*)(wsb + 19922944);   // 512 KB
  u16*   ff1    = (u16*)(wsb + 20971520);   // 16 MB [4096][2048]
  float* ff2    = (float*)(wsb + 37748736); // 2 MB

  detect_dtype<<<1, 256, 0, stream>>>(x, dflag);
  // zero Oacc, Lacc, counts, cursor in one shot (proven r9)
  hipMemsetAsync(wsb + 3145728, 0, 2195456, stream);
  // zero ff2 (atomic accumulate target; disjoint, safe at stream top)
  hipMemsetAsync(ff2, 0, 2097152, stream);

  // degree + CSR (shared by all 3 GCN layers)
  count_deg<<<(E + 255) / 256, 256, 0, stream>>>(edst, counts, E);
  scan4096<<<1, 1024, 0, stream>>>(counts, offs, dinv);
  fill_csr<<<(E + 255) / 256, 256, 0, stream>>>(esrc, edst, offs, cursor, csr, E);

  // transformer encoder layer
  gemm_mfma<<<dim3(6, 64), 256, 0, stream>>>(x, in_proj_w, in_proj_b, qkQK, Vg,
      384, 128, 128, 128, 0, 0, /*bias+Araw+qkv*/ 8 | 16 | 128, dflag, nullptr);
  attn_part<<<dim3(64, 4, 4), 256, 0, stream>>>(qkQK, Vg, Oacc, Lacc);
  gemm_mfma<<<dim3(2, 64), 256, 0, stream>>>(Oacc, out_proj_w, out_proj_b, ao, nullptr,
      128, 128, 128, 128, 0, 0, /*f32out+bias+Af32*/ 4 | 8 | 64, dflag, Lacc);
  ln_res<<<1024, 256, 0, stream>>>(x, 1, ao, nullptr, ln1_g, ln1_b, y_bf, y_f32, dflag);
  // FFN: one w1 call (N=2048), then z=8 K-split atomic w2 (1024 blocks);
  // ffn_b2 applied in ln2's rbias (atomic path would add it 8x)
  gemm_mfma<<<dim3(32, 64), 256, 0, stream>>>(y_bf, ffn_w1, ffn_b1, ff1, nullptr,
      2048, 128, 128, 128, 0, 0, /*relu+bias*/ 1 | 8, dflag, nullptr);
  gemm_mfma<<<dim3(2, 64, 8), 256, 0, stream>>>(ff1, ffn_w2, nullptr, ff2, nullptr,
      128, 2048, 2048, 2048, 0, 0, /*f32 atomic*/ 4 | 32, dflag, nullptr);
  ln_res<<<1024, 256, 0, stream>>>(y_f32, 0, ff2, ffn_b2, ln2_g, ln2_b, z_bf, nullptr, dflag);

  // 3-layer GCN; aggregation commutes with the weight multiply
  gcn_gather<<<512, 256, 0, stream>>>(z_bf, dinv, offs, csr, nullptr, az, 128, 0, 0, dflag);
  gemm_mfma<<<dim3(4, 64), 256, 0, stream>>>(az, g1w, g1b, h1, nullptr,
      256, 128, 128, 128, 0, 0, /*relu+bias*/ 1 | 8, dflag, nullptr);
  gcn_gather<<<1024, 256, 0, stream>>>(h1, dinv, offs, csr, nullptr, ah1, 256, 0, 0, dflag);
  gemm_mfma<<<dim3(4, 64), 256, 0, stream>>>(ah1, g2w, g2b, h2, nullptr,
      256, 256, 256, 256, 0, 0, /*relu+bias*/ 1 | 8, dflag, nullptr);
  gemm_mfma<<<dim3(1, 64), 256, 0, stream>>>(h2, g3w, nullptr, t3, nullptr,
      64, 256, 256, 256, 0, 0, 0, dflag, nullptr);
  gcn_gather<<<256, 256, 0, stream>>>(t3, dinv, offs, csr, g3b, d_out, 64, 0, 1, dflag);
}

// Round 15
// 304.901 us; speedup vs baseline: 1.0711x; 1.0191x over previous
//
#include <hip/hip_runtime.h>

// WaterLevelGCN r15: r14 with attn_part restructured to BK=128 keys/iter
// (8 iters x 3 barriers = 24, was 48; 36KB LDS -- below the 48KB cliff that
// silently killed r10-r12 kernels). Everything else r14-verbatim.
// Fully disjoint layout (ws = 256 MiB), no aliasing:
// qkQK@0(2M) Vg@2M(1M) Oacc@3M(2M) Lacc@5242880 counts@5308416 cursor@5324800
// offs@5341184 csr@5357572 dinv@5881860 dflag@5898244 y_f32@6291456(2M)
// y_bf@8388608(1M) ao@9437184(2M) z@11534336(1M) az@12582912(1M)
// h1@13631488(2M) ah1@15728640(2M) h2@17825792(2M) t3@19922944(.5M)
// ff1@20971520(16M) ff2@37748736(2M)

typedef unsigned short u16;
typedef __attribute__((ext_vector_type(8))) short bf16x8;
typedef __attribute__((ext_vector_type(4))) float f32x4;

__device__ __forceinline__ float b2f(u16 u) {
  union { unsigned int i; float f; } x; x.i = ((unsigned int)u) << 16; return x.f;
}
__device__ __forceinline__ u16 f2b(float f) {
  union { float f; unsigned int i; } x; x.f = f;
  unsigned int r = x.i + 0x7FFFu + ((x.i >> 16) & 1u);
  return (u16)(r >> 16);
}
__device__ __forceinline__ float ld1(const void* p, size_t i, int bf) {
  return bf ? b2f(((const u16*)p)[i]) : ((const float*)p)[i];
}

// ---------------- dtype detect (insurance; proven bf16) ----------------
__global__ void detect_dtype(const void* x, int* flag) {
  __shared__ int cnt;
  if (threadIdx.x == 0) cnt = 0;
  __syncthreads();
  const u16* p = (const u16*)x;
  int c = 0;
  for (int i = threadIdx.x; i < 4096; i += 256) {
    int e = (p[i] >> 7) & 0xFF;
    if (e >= 140) c++;
  }
  atomicAdd(&cnt, c);
  __syncthreads();
  if (threadIdx.x == 0) flag[0] = (cnt < 64) ? 1 : 0;
}

// ------------- GEMM: C[.,N] = A[M,K]@B[N,K]^T, bf16 MFMA, 64x64 tile -------
// BK=128 staging, XOR-swizzled LDS (proven r9). 32 KB LDS.
// flags: 1=relu, 2=acc, 4=C f32, 8=bias, 16=A raw input, 32=atomic f32 acc,
//        64=A f32 internal (divL per-head normalize), 128=in_proj special.
__global__ __launch_bounds__(256) void gemm_mfma(
    const void* __restrict__ A, const void* __restrict__ B,
    const void* __restrict__ bias, void* __restrict__ C, void* __restrict__ C2,
    int N, int K, int lda, int ldb, int bRow0, int bK0, int flags,
    const int* __restrict__ dflag, const float* __restrict__ divL)
{
  const int wbf = *dflag;
  const int abf = (flags & 64) ? 0 : ((flags & 16) ? wbf : 1);
  __shared__ u16 As[64][128];
  __shared__ u16 Bs[64][128];
  const int tid = threadIdx.x;
  const int wv = tid >> 6, l = tid & 63;
  const int lr = l & 15, lq = l >> 4;
  const int row0 = blockIdx.y * 64, col0 = blockIdx.x * 64;
  const int qr = 32 * (wv >> 1), qc = 32 * (wv & 1);
  const int sr = tid >> 2, sb = tid & 3;
  const int Kz = K / gridDim.z;
  const int k0 = blockIdx.z * Kz;
  f32x4 acc[2][2] = {};
  for (int kt = k0; kt < k0 + Kz; kt += 128) {
    __syncthreads();
#pragma unroll
    for (int g = 0; g < 4; g++) {
      int b = sb + 4 * g;
      int cc = b * 8;
      int bs = (b ^ (sr & 15)) * 8;
      size_t offA = (size_t)(row0 + sr) * lda + kt + cc;
      if (abf) {
        *(bf16x8*)&As[sr][bs] = *(const bf16x8*)((const u16*)A + offA);
      } else {
        const float* pf = (const float*)A + offA;
        float iv = divL
            ? 1.0f / divL[(size_t)((kt + cc) >> 5) * 4096 + row0 + sr]
            : 1.0f;
        float4 f0 = *(const float4*)pf, f1 = *(const float4*)(pf + 4);
        u16 t[8] = {f2b(f0.x*iv), f2b(f0.y*iv), f2b(f0.z*iv), f2b(f0.w*iv),
                    f2b(f1.x*iv), f2b(f1.y*iv), f2b(f1.z*iv), f2b(f1.w*iv)};
        *(bf16x8*)&As[sr][bs] = *(bf16x8*)t;
      }
      size_t offB = (size_t)(bRow0 + col0 + sr) * ldb + bK0 + kt + cc;
      if (wbf) {
        *(bf16x8*)&Bs[sr][bs] = *(const bf16x8*)((const u16*)B + offB);
      } else {
        const float* pf = (const float*)B + offB;
        float4 f0 = *(const float4*)pf, f1 = *(const float4*)(pf + 4);
        u16 t[8] = {f2b(f0.x), f2b(f0.y), f2b(f0.z), f2b(f0.w),
                    f2b(f1.x), f2b(f1.y), f2b(f1.z), f2b(f1.w)};
        *(bf16x8*)&Bs[sr][bs] = *(bf16x8*)t;
      }
    }
    __syncthreads();
#pragma unroll
    for (int kk = 0; kk < 4; kk++) {
      int bx = ((4 * kk + lq) ^ lr) * 8;
      bf16x8 a0 = *(const bf16x8*)&As[qr + lr][bx];
      bf16x8 a1 = *(const bf16x8*)&As[qr + 16 + lr][bx];
      bf16x8 b0 = *(const bf16x8*)&Bs[qc + lr][bx];
      bf16x8 b1 = *(const bf16x8*)&Bs[qc + 16 + lr][bx];
      acc[0][0] = __builtin_amdgcn_mfma_f32_16x16x32_bf16(a0, b0, acc[0][0], 0, 0, 0);
      acc[0][1] = __builtin_amdgcn_mfma_f32_16x16x32_bf16(a0, b1, acc[0][1], 0, 0, 0);
      acc[1][0] = __builtin_amdgcn_mfma_f32_16x16x32_bf16(a1, b0, acc[1][0], 0, 0, 0);
      acc[1][1] = __builtin_amdgcn_mfma_f32_16x16x32_bf16(a1, b1, acc[1][1], 0, 0, 0);
    }
  }
  if ((flags & 128) && col0 >= 256) {
#pragma unroll
    for (int i = 0; i < 2; i++) {
#pragma unroll
      for (int j = 0; j < 2; j++) {
        int colg = col0 + qc + 16 * j + lr;
        int d = colg - 256;
        int rowbase = row0 + qr + 16 * i + lq * 4;
        float bb = ld1(bias, colg, wbf);
        ushort4 pv = make_ushort4(
            f2b(acc[i][j][0] + bb), f2b(acc[i][j][1] + bb),
            f2b(acc[i][j][2] + bb), f2b(acc[i][j][3] + bb));
        *(ushort4*)((u16*)C2 + (size_t)d * 4096 + rowbase) = pv;
      }
    }
    return;
  }
  const int ldc = (flags & 128) ? 256 : N;
#pragma unroll
  for (int i = 0; i < 2; i++) {
#pragma unroll
    for (int j = 0; j < 2; j++) {
#pragma unroll
      for (int r = 0; r < 4; r++) {
        int row = row0 + qr + 16 * i + lq * 4 + r;
        int col = col0 + qc + 16 * j + lr;
        float v = acc[i][j][r];
        if (flags & 8) v += ld1(bias, bRow0 + col, wbf);
        if (flags & 1) v = fmaxf(v, 0.f);
        size_t idx = (size_t)row * ldc + col;
        if (flags & 32) {
          atomicAdd(&((float*)C)[idx], v);
        } else if (flags & 4) {
          float* Cf = (float*)C;
          if (flags & 2) v += Cf[idx];
          Cf[idx] = v;
        } else {
          ((u16*)C)[idx] = f2b(v);
        }
      }
    }
  }
}

// ------ split-K flash attention, fixed-shift softmax, BK=128 keys/iter -----
// 36KB LDS (below 48KB cliff). 8 iters x 3 barriers. Same math as r9/r14.
__global__ __launch_bounds__(256) void attn_part(
    const u16* __restrict__ qk, const u16* __restrict__ Vg,
    float* __restrict__ O, float* __restrict__ L)
{
  const int qt = blockIdx.x, h = blockIdx.y, kc = blockIdx.z;
  const int n0 = qt * 64;
  __shared__ u16 Qs[64][32];
  __shared__ u16 Ks[128][32];
  __shared__ u16 Vt[32][128];
  __shared__ u16 Ps[64][128];
  const int tid = threadIdx.x;
  const int wv = tid >> 6, l = tid & 63;
  const int lr = l & 15, lq = l >> 4;
  const int sr = tid >> 2, sb = tid & 3;   // Qs: 64 rows x 4 chunks
  const int kr = tid >> 1, kb = tid & 1;   // Ks: 128 rows x 2 chunks/thread x2
  const int vr = tid >> 3, vb = tid & 7;   // Vt: 32 rows x 8 chunks/thread x2
  *(bf16x8*)&Qs[sr][(sb ^ (sr & 3)) * 8] =
      *(const bf16x8*)(qk + (size_t)(n0 + sr) * 256 + h * 32 + sb * 8);
  __syncthreads();
  const float sc = 0.17677669529663687f;  // 1/sqrt(32), folded into Q frag
  bf16x8 qf;
  {
    bf16x8 qraw = *(const bf16x8*)&Qs[16 * wv + lr][(lq ^ (lr & 3)) * 8];
#pragma unroll
    for (int t = 0; t < 8; t++)
      qf[t] = (short)f2b(b2f((u16)qraw[t]) * sc);
  }
  f32x4 o0 = {}, o1 = {};
  float psum[4] = {0.f, 0.f, 0.f, 0.f};
  for (int t = 0; t < 8; t++) {
    const int m0 = kc * 1024 + t * 128;
    __syncthreads();   // prior-iter reads done before restage
#pragma unroll
    for (int cc = 0; cc < 2; cc++) {
      int ch = kb + 2 * cc;   // 0..3
      *(bf16x8*)&Ks[kr][(ch ^ (kr & 3)) * 8] =
          *(const bf16x8*)(qk + (size_t)(m0 + kr) * 256 + 128 + h * 32 + ch * 8);
    }
#pragma unroll
    for (int cc = 0; cc < 2; cc++) {
      int ch = vb + 8 * cc;   // 0..15
      *(bf16x8*)&Vt[vr][(ch ^ (vr & 15)) * 8] =
          *(const bf16x8*)(Vg + (size_t)(h * 32 + vr) * 4096 + m0 + ch * 8);
    }
    __syncthreads();
    f32x4 s[8];
#pragma unroll
    for (int jt = 0; jt < 8; jt++) {
      bf16x8 kf = *(const bf16x8*)&Ks[16 * jt + lr][(lq ^ (lr & 3)) * 8];
      f32x4 z = {};
      s[jt] = __builtin_amdgcn_mfma_f32_16x16x32_bf16(qf, kf, z, 0, 0, 0);
    }
#pragma unroll
    for (int jt = 0; jt < 8; jt++)
#pragma unroll
      for (int r = 0; r < 4; r++) {
        float p = __expf(s[jt][r]);
        psum[r] += p;
        int qrow = 16 * wv + lq * 4 + r;
        int ch = 2 * jt + (lr >> 3);         // 0..15
        Ps[qrow][(ch ^ (qrow & 15)) * 8 + (lr & 7)] = f2b(p);
      }
    __syncthreads();   // P visible block-wide (proven required in r4)
#pragma unroll
    for (int kk = 0; kk < 4; kk++) {
      int prow = 16 * wv + lr;
      bf16x8 pf = *(const bf16x8*)&Ps[prow][((4 * kk + lq) ^ (lr & 15)) * 8];
      bf16x8 v0 = *(const bf16x8*)&Vt[lr][((4 * kk + lq) ^ (lr & 15)) * 8];
      bf16x8 v1 = *(const bf16x8*)&Vt[16 + lr][((4 * kk + lq) ^ (lr & 15)) * 8];
      o0 = __builtin_amdgcn_mfma_f32_16x16x32_bf16(pf, v0, o0, 0, 0, 0);
      o1 = __builtin_amdgcn_mfma_f32_16x16x32_bf16(pf, v1, o1, 0, 0, 0);
    }
  }
#pragma unroll
  for (int r = 0; r < 4; r++) {
    int row = n0 + 16 * wv + lq * 4 + r;
    atomicAdd(&O[(size_t)row * 128 + h * 32 + lr],      o0[r]);
    atomicAdd(&O[(size_t)row * 128 + h * 32 + 16 + lr], o1[r]);
    float ps = psum[r];
    ps += __shfl_xor(ps, 1); ps += __shfl_xor(ps, 2);
    ps += __shfl_xor(ps, 4); ps += __shfl_xor(ps, 8);
    if (lr == 0) atomicAdd(&L[h * 4096 + row], ps);
  }
}

// ------- LayerNorm(A + R (+ rbias[col]))*g + b (proven r9) -----------------
__global__ __launch_bounds__(256) void ln_res(
    const void* __restrict__ A, int a_mode, const float* __restrict__ R,
    const void* __restrict__ rbias,
    const void* __restrict__ g, const void* __restrict__ b,
    u16* __restrict__ out_bf, float* __restrict__ out_f32,
    const int* __restrict__ dflag)
{
  const int wbf = *dflag;
  const int abf = a_mode ? wbf : 0;
  int row = blockIdx.x * 4 + (threadIdx.x >> 6);
  int lane = threadIdx.x & 63;
  size_t i0 = (size_t)row * 128 + lane, i1 = i0 + 64;
  float v0 = ld1(A, i0, abf) + R[i0];
  float v1 = ld1(A, i1, abf) + R[i1];
  if (rbias) { v0 += ld1(rbias, lane, wbf); v1 += ld1(rbias, lane + 64, wbf); }
  float s = v0 + v1, sq = v0 * v0 + v1 * v1;
  for (int off = 32; off; off >>= 1) { s += __shfl_down(s, off); sq += __shfl_down(sq, off); }
  s = __shfl(s, 0); sq = __shfl(sq, 0);
  float mu = s * (1.f / 128.f);
  float var = sq * (1.f / 128.f) - mu * mu;
  float rs = rsqrtf(var + 1e-5f);
  float r0 = (v0 - mu) * rs * ld1(g, lane, wbf) + ld1(b, lane, wbf);
  float r1 = (v1 - mu) * rs * ld1(g, lane + 64, wbf) + ld1(b, lane + 64, wbf);
  out_bf[i0] = f2b(r0);
  out_bf[i1] = f2b(r1);
  if (out_f32) { out_f32[i0] = r0; out_f32[i1] = r1; }
}

// ---------------- degree / CSR build (proven r9) ----------------
__global__ void count_deg(const int* __restrict__ dst, int* __restrict__ counts, int E) {
  int e = blockIdx.x * 256 + threadIdx.x;
  if (e < E) atomicAdd(&counts[dst[e]], 1);
}

__global__ __launch_bounds__(1024) void scan4096(
    const int* __restrict__ counts, int* __restrict__ offs,
    float* __restrict__ dinv)
{
  __shared__ int buf[4096];
  __shared__ int part[1024];
  int t = threadIdx.x;
  for (int i = t; i < 4096; i += 1024) buf[i] = counts[i];
  __syncthreads();
  int base = t * 4;
  int s = buf[base] + buf[base + 1] + buf[base + 2] + buf[base + 3];
  part[t] = s;
  __syncthreads();
  for (int off = 1; off < 1024; off <<= 1) {
    int v = (t >= off) ? part[t - off] : 0;
    __syncthreads();
    part[t] += v;
    __syncthreads();
  }
  int run = (t == 0) ? 0 : part[t - 1];
  for (int j = 0; j < 4; j++) {
    int c = buf[base + j];
    offs[base + j] = run;
    dinv[base + j] = rsqrtf((float)(c + 1));
    run += c;
  }
  if (t == 1023) offs[4096] = run;
}

__global__ void fill_csr(const int* __restrict__ src, const int* __restrict__ dst,
                         const int* __restrict__ offs, int* __restrict__ cursor,
                         int* __restrict__ csr, int E) {
  int e = blockIdx.x * 256 + threadIdx.x;
  if (e < E) {
    int t = dst[e];
    int pos = offs[t] + atomicAdd(&cursor[t], 1);
    csr[pos] = src[e];
  }
}

// -------- GCN gather, ushort4-vectorized (proven r9) -----------------------
__global__ __launch_bounds__(256) void gcn_gather(
    const u16* __restrict__ h, const float* __restrict__ dinv,
    const int* __restrict__ offs, const int* __restrict__ csr,
    const void* __restrict__ bias, void* __restrict__ out,
    int F, int relu, int final_out, const int* __restrict__ dflag)
{
  const int wbf = *dflag;
  const int tpn = F >> 2;
  const int node = blockIdx.x * (256 / tpn) + threadIdx.x / tpn;
  const int f = (threadIdx.x % tpn) * 4;
  float di = dinv[node];
  ushort4 hv = *(const ushort4*)(h + (size_t)node * F + f);
  float a0 = di * b2f(hv.x), a1 = di * b2f(hv.y);
  float a2 = di * b2f(hv.z), a3 = di * b2f(hv.w);
  int e0 = offs[node], e1 = offs[node + 1];
  for (int e = e0; e < e1; e++) {
    int s = csr[e];
    float ds = dinv[s];
    ushort4 sv = *(const ushort4*)(h + (size_t)s * F + f);
    a0 += ds * b2f(sv.x); a1 += ds * b2f(sv.y);
    a2 += ds * b2f(sv.z); a3 += ds * b2f(sv.w);
  }
  float b0 = bias ? ld1(bias, f, wbf)     : 0.f;
  float b1 = bias ? ld1(bias, f + 1, wbf) : 0.f;
  float b2 = bias ? ld1(bias, f + 2, wbf) : 0.f;
  float b3 = bias ? ld1(bias, f + 3, wbf) : 0.f;
  float v0 = a0 * di + b0, v1 = a1 * di + b1;
  float v2 = a2 * di + b2, v3 = a3 * di + b3;
  if (relu) {
    v0 = fmaxf(v0, 0.f); v1 = fmaxf(v1, 0.f);
    v2 = fmaxf(v2, 0.f); v3 = fmaxf(v3, 0.f);
  }
  size_t idx = (size_t)node * F + f;
  if (!final_out || wbf) {
    *(ushort4*)((u16*)out + idx) = make_ushort4(f2b(v0), f2b(v1), f2b(v2), f2b(v3));
  } else {
    *(float4*)((float*)out + idx) = make_float4(v0, v1, v2, v3);
  }
}

extern "C" void kernel_launch(void* const* d_in, const int* in_sizes, int n_in,
                              void* d_out, int out_size, void* d_ws, size_t ws_size,
                              hipStream_t stream)
{
  const void* x          = d_in[0];
  const int*  edge       = (const int*)d_in[1];
  const void* in_proj_w  = d_in[2];
  const void* in_proj_b  = d_in[3];
  const void* out_proj_w = d_in[4];
  const void* out_proj_b = d_in[5];
  const void* ln1_g      = d_in[6];
  const void* ln1_b      = d_in[7];
  const void* ffn_w1     = d_in[8];
  const void* ffn_b1     = d_in[9];
  const void* ffn_w2     = d_in[10];
  const void* ffn_b2     = d_in[11];
  const void* ln2_g      = d_in[12];
  const void* ln2_b      = d_in[13];
  const void* g1w        = d_in[14];
  const void* g1b        = d_in[15];
  const void* g2w        = d_in[16];
  const void* g2b        = d_in[17];
  const void* g3w        = d_in[18];
  const void* g3b        = d_in[19];
  const int E = in_sizes[1] / 2;
  const int* esrc = edge;
  const int* edst = edge + E;

  char* wsb     = (char*)d_ws;
  // fully disjoint layout (ws = 256 MiB)
  u16*   qkQK   = (u16*)(wsb + 0);          // 2 MB
  u16*   Vg     = (u16*)(wsb + 2097152);    // 1 MB
  float* Oacc   = (float*)(wsb + 3145728);  // 2 MB
  float* Lacc   = (float*)(wsb + 5242880);  // 64 KB
  int*   counts = (int*)(wsb + 5308416);
  int*   cursor = (int*)(wsb + 5324800);
  int*   offs   = (int*)(wsb + 5341184);
  int*   csr    = (int*)(wsb + 5357572);
  float* dinv   = (float*)(wsb + 5881860);
  int*   dflag  = (int*)(wsb + 5898244);
  float* y_f32  = (float*)(wsb + 6291456);  // 2 MB
  u16*   y_bf   = (u16*)(wsb + 8388608);    // 1 MB
  float* ao     = (float*)(wsb + 9437184);  // 2 MB
  u16*   z_bf   = (u16*)(wsb + 11534336);   // 1 MB
  u16*   az     = (u16*)(wsb + 12582912);   // 1 MB
  u16*   h1     = (u16*)(wsb + 13631488);   // 2 MB
  u16*   ah1    = (u16*)(wsb + 15728640);   // 2 MB
  u16*   h2     = (u16*)(wsb + 17825792);   // 2 MB
  u16*   t3     = (u16*)(wsb + 19922944);   // 512 KB
  u16*   ff1    = (u16*)(wsb + 20971520);   // 16 MB [4096][2048]
  float* ff2    = (float*)(wsb + 37748736); // 2 MB

  detect_dtype<<<1, 256, 0, stream>>>(x, dflag);
  // zero Oacc, Lacc, counts, cursor in one shot (proven r9)
  hipMemsetAsync(wsb + 3145728, 0, 2195456, stream);
  // zero ff2 (atomic accumulate target; disjoint, safe at stream top)
  hipMemsetAsync(ff2, 0, 2097152, stream);

  // degree + CSR (shared by all 3 GCN layers)
  count_deg<<<(E + 255) / 256, 256, 0, stream>>>(edst, counts, E);
  scan4096<<<1, 1024, 0, stream>>>(counts, offs, dinv);
  fill_csr<<<(E + 255) / 256, 256, 0, stream>>>(esrc, edst, offs, cursor, csr, E);

  // transformer encoder layer
  gemm_mfma<<<dim3(6, 64), 256, 0, stream>>>(x, in_proj_w, in_proj_b, qkQK, Vg,
      384, 128, 128, 128, 0, 0, /*bias+Araw+qkv*/ 8 | 16 | 128, dflag, nullptr);
  attn_part<<<dim3(64, 4, 4), 256, 0, stream>>>(qkQK, Vg, Oacc, Lacc);
  gemm_mfma<<<dim3(2, 64), 256, 0, stream>>>(Oacc, out_proj_w, out_proj_b, ao, nullptr,
      128, 128, 128, 128, 0, 0, /*f32out+bias+Af32*/ 4 | 8 | 64, dflag, Lacc);
  ln_res<<<1024, 256, 0, stream>>>(x, 1, ao, nullptr, ln1_g, ln1_b, y_bf, y_f32, dflag);
  // FFN: one w1 call (N=2048), then z=8 K-split atomic w2 (1024 blocks);
  // ffn_b2 applied in ln2's rbias (atomic path would add it 8x)
  gemm_mfma<<<dim3(32, 64), 256, 0, stream>>>(y_bf, ffn_w1, ffn_b1, ff1, nullptr,
      2048, 128, 128, 128, 0, 0, /*relu+bias*/ 1 | 8, dflag, nullptr);
  gemm_mfma<<<dim3(2, 64, 8), 256, 0, stream>>>(ff1, ffn_w2, nullptr, ff2, nullptr,
      128, 2048, 2048, 2048, 0, 0, /*f32 atomic*/ 4 | 32, dflag, nullptr);
  ln_res<<<1024, 256, 0, stream>>>(y_f32, 0, ff2, ffn_b2, ln2_g, ln2_b, z_bf, nullptr, dflag);

  // 3-layer GCN; aggregation commutes with the weight multiply
  gcn_gather<<<512, 256, 0, stream>>>(z_bf, dinv, offs, csr, nullptr, az, 128, 0, 0, dflag);
  gemm_mfma<<<dim3(4, 64), 256, 0, stream>>>(az, g1w, g1b, h1, nullptr,
      256, 128, 128, 128, 0, 0, /*relu+bias*/ 1 | 8, dflag, nullptr);
  gcn_gather<<<1024, 256, 0, stream>>>(h1, dinv, offs, csr, nullptr, ah1, 256, 0, 0, dflag);
  gemm_mfma<<<dim3(4, 64), 256, 0, stream>>>(ah1, g2w, g2b, h2, nullptr,
      256, 256, 256, 256, 0, 0, /*relu+bias*/ 1 | 8, dflag, nullptr);
  gemm_mfma<<<dim3(1, 64), 256, 0, stream>>>(h2, g3w, nullptr, t3, nullptr,
      64, 256, 256, 256, 0, 0, 0, dflag, nullptr);
  gcn_gather<<<256, 256, 0, stream>>>(t3, dinv, offs, csr, g3b, d_out, 64, 0, 1, dflag);
}

// Round 16
// 296.732 us; speedup vs baseline: 1.1006x; 1.0275x over previous
//
#include <hip/hip_runtime.h>

// WaterLevelGCN r16: r15 compute verbatim; dispatch-chain reduction only.
// (1) single memset (Oacc|Lacc|ff2|counts|cursor contiguous), (2) detect+
// count_deg merged (513 blocks), (3) fill_csr+in_proj merged (896 blocks).
// LESSON (r10-r12): 48KB-LDS kernels silently never ran; keep LDS <= 44KB.
// Disjoint layout (ws = 256 MiB):
// qkQK@0(2M) Vg@2M(1M) | zero-region: Oacc@3145728(2M) Lacc@5242880(64K)
// ff2@5308416(2M) counts@7405568 cursor@7421952 | offs@7438336 csr@7454724
// dinv@7979012 dflag@7995396 | y_f32@8388608(2M) y_bf@10485760(1M)
// ao@11534336(2M) z@13631488(1M) az@14680064(1M) h1@15728640(2M)
// ah1@17825792(2M) h2@19922944(2M) t3@22020096(.5M) ff1@23068672(16M)

typedef unsigned short u16;
typedef __attribute__((ext_vector_type(8))) short bf16x8;
typedef __attribute__((ext_vector_type(4))) float f32x4;

__device__ __forceinline__ float b2f(u16 u) {
  union { unsigned int i; float f; } x; x.i = ((unsigned int)u) << 16; return x.f;
}
__device__ __forceinline__ u16 f2b(float f) {
  union { float f; unsigned int i; } x; x.f = f;
  unsigned int r = x.i + 0x7FFFu + ((x.i >> 16) & 1u);
  return (u16)(r >> 16);
}
__device__ __forceinline__ float ld1(const void* p, size_t i, int bf) {
  return bf ? b2f(((const u16*)p)[i]) : ((const float*)p)[i];
}

// ------------- GEMM device body (r9/r15-proven math, verbatim) -------------
// flags: 1=relu, 2=acc, 4=C f32, 8=bias, 16=A raw input, 32=atomic f32 acc,
//        64=A f32 internal (divL per-head normalize), 128=in_proj special.
__device__ void gemm_body(
    int bx, int by, int bz, int nz,
    const void* __restrict__ A, const void* __restrict__ B,
    const void* __restrict__ bias, void* __restrict__ C, void* __restrict__ C2,
    int N, int K, int lda, int ldb, int bRow0, int bK0, int flags,
    const int* __restrict__ dflag, const float* __restrict__ divL)
{
  const int wbf = *dflag;
  const int abf = (flags & 64) ? 0 : ((flags & 16) ? wbf : 1);
  __shared__ u16 As[64][128];
  __shared__ u16 Bs[64][128];
  const int tid = threadIdx.x;
  const int wv = tid >> 6, l = tid & 63;
  const int lr = l & 15, lq = l >> 4;
  const int row0 = by * 64, col0 = bx * 64;
  const int qr = 32 * (wv >> 1), qc = 32 * (wv & 1);
  const int sr = tid >> 2, sb = tid & 3;
  const int Kz = K / nz;
  const int k0 = bz * Kz;
  f32x4 acc[2][2] = {};
  for (int kt = k0; kt < k0 + Kz; kt += 128) {
    __syncthreads();
#pragma unroll
    for (int g = 0; g < 4; g++) {
      int b = sb + 4 * g;
      int cc = b * 8;
      int bs = (b ^ (sr & 15)) * 8;
      size_t offA = (size_t)(row0 + sr) * lda + kt + cc;
      if (abf) {
        *(bf16x8*)&As[sr][bs] = *(const bf16x8*)((const u16*)A + offA);
      } else {
        const float* pf = (const float*)A + offA;
        float iv = divL
            ? 1.0f / divL[(size_t)((kt + cc) >> 5) * 4096 + row0 + sr]
            : 1.0f;
        float4 f0 = *(const float4*)pf, f1 = *(const float4*)(pf + 4);
        u16 t[8] = {f2b(f0.x*iv), f2b(f0.y*iv), f2b(f0.z*iv), f2b(f0.w*iv),
                    f2b(f1.x*iv), f2b(f1.y*iv), f2b(f1.z*iv), f2b(f1.w*iv)};
        *(bf16x8*)&As[sr][bs] = *(bf16x8*)t;
      }
      size_t offB = (size_t)(bRow0 + col0 + sr) * ldb + bK0 + kt + cc;
      if (wbf) {
        *(bf16x8*)&Bs[sr][bs] = *(const bf16x8*)((const u16*)B + offB);
      } else {
        const float* pf = (const float*)B + offB;
        float4 f0 = *(const float4*)pf, f1 = *(const float4*)(pf + 4);
        u16 t[8] = {f2b(f0.x), f2b(f0.y), f2b(f0.z), f2b(f0.w),
                    f2b(f1.x), f2b(f1.y), f2b(f1.z), f2b(f1.w)};
        *(bf16x8*)&Bs[sr][bs] = *(bf16x8*)t;
      }
    }
    __syncthreads();
#pragma unroll
    for (int kk = 0; kk < 4; kk++) {
      int bxs = ((4 * kk + lq) ^ lr) * 8;
      bf16x8 a0 = *(const bf16x8*)&As[qr + lr][bxs];
      bf16x8 a1 = *(const bf16x8*)&As[qr + 16 + lr][bxs];
      bf16x8 b0 = *(const bf16x8*)&Bs[qc + lr][bxs];
      bf16x8 b1 = *(const bf16x8*)&Bs[qc + 16 + lr][bxs];
      acc[0][0] = __builtin_amdgcn_mfma_f32_16x16x32_bf16(a0, b0, acc[0][0], 0, 0, 0);
      acc[0][1] = __builtin_amdgcn_mfma_f32_16x16x32_bf16(a0, b1, acc[0][1], 0, 0, 0);
      acc[1][0] = __builtin_amdgcn_mfma_f32_16x16x32_bf16(a1, b0, acc[1][0], 0, 0, 0);
      acc[1][1] = __builtin_amdgcn_mfma_f32_16x16x32_bf16(a1, b1, acc[1][1], 0, 0, 0);
    }
  }
  if ((flags & 128) && col0 >= 256) {
#pragma unroll
    for (int i = 0; i < 2; i++) {
#pragma unroll
      for (int j = 0; j < 2; j++) {
        int colg = col0 + qc + 16 * j + lr;
        int d = colg - 256;
        int rowbase = row0 + qr + 16 * i + lq * 4;
        float bb = ld1(bias, colg, wbf);
        ushort4 pv = make_ushort4(
            f2b(acc[i][j][0] + bb), f2b(acc[i][j][1] + bb),
            f2b(acc[i][j][2] + bb), f2b(acc[i][j][3] + bb));
        *(ushort4*)((u16*)C2 + (size_t)d * 4096 + rowbase) = pv;
      }
    }
    return;
  }
  const int ldc = (flags & 128) ? 256 : N;
#pragma unroll
  for (int i = 0; i < 2; i++) {
#pragma unroll
    for (int j = 0; j < 2; j++) {
#pragma unroll
      for (int r = 0; r < 4; r++) {
        int row = row0 + qr + 16 * i + lq * 4 + r;
        int col = col0 + qc + 16 * j + lr;
        float v = acc[i][j][r];
        if (flags & 8) v += ld1(bias, bRow0 + col, wbf);
        if (flags & 1) v = fmaxf(v, 0.f);
        size_t idx = (size_t)row * ldc + col;
        if (flags & 32) {
          atomicAdd(&((float*)C)[idx], v);
        } else if (flags & 4) {
          float* Cf = (float*)C;
          if (flags & 2) v += Cf[idx];
          Cf[idx] = v;
        } else {
          ((u16*)C)[idx] = f2b(v);
        }
      }
    }
  }
}

__global__ __launch_bounds__(256) void gemm_mfma(
    const void* __restrict__ A, const void* __restrict__ B,
    const void* __restrict__ bias, void* __restrict__ C, void* __restrict__ C2,
    int N, int K, int lda, int ldb, int bRow0, int bK0, int flags,
    const int* __restrict__ dflag, const float* __restrict__ divL)
{
  gemm_body(blockIdx.x, blockIdx.y, blockIdx.z, gridDim.z,
            A, B, bias, C, C2, N, K, lda, ldb, bRow0, bK0, flags, dflag, divL);
}

// ------- merged: block 0 = dtype detect; blocks 1..512 = count_deg ---------
__global__ __launch_bounds__(256) void det_count(
    const void* __restrict__ x, int* __restrict__ flag,
    const int* __restrict__ dst, int* __restrict__ counts, int E)
{
  if (blockIdx.x == 0) {
    __shared__ int cnt;
    if (threadIdx.x == 0) cnt = 0;
    __syncthreads();
    const u16* p = (const u16*)x;
    int c = 0;
    for (int i = threadIdx.x; i < 4096; i += 256) {
      int e = (p[i] >> 7) & 0xFF;
      if (e >= 140) c++;
    }
    atomicAdd(&cnt, c);
    __syncthreads();
    if (threadIdx.x == 0) flag[0] = (cnt < 64) ? 1 : 0;
  } else {
    int e = (blockIdx.x - 1) * 256 + threadIdx.x;
    if (e < E) atomicAdd(&counts[dst[e]], 1);
  }
}

// ------- merged: blocks 0..383 = in_proj GEMM; 384..895 = fill_csr ---------
__global__ __launch_bounds__(256) void csr_inproj(
    const void* __restrict__ xin, const void* __restrict__ W,
    const void* __restrict__ bias, void* __restrict__ qkQK, void* __restrict__ Vg,
    const int* __restrict__ dflag,
    const int* __restrict__ src, const int* __restrict__ dst,
    const int* __restrict__ offs, int* __restrict__ cursor,
    int* __restrict__ csr, int E)
{
  if (blockIdx.x < 384) {
    gemm_body(blockIdx.x % 6, blockIdx.x / 6, 0, 1,
              xin, W, bias, qkQK, Vg, 384, 128, 128, 128, 0, 0,
              /*bias+Araw+qkv*/ 8 | 16 | 128, dflag, nullptr);
  } else {
    int e = (blockIdx.x - 384) * 256 + threadIdx.x;
    if (e < E) {
      int t = dst[e];
      int pos = offs[t] + atomicAdd(&cursor[t], 1);
      csr[pos] = src[e];
    }
  }
}

// ------ split-K flash attention, fixed-shift softmax, BK=128 (r15) ---------
__global__ __launch_bounds__(256) void attn_part(
    const u16* __restrict__ qk, const u16* __restrict__ Vg,
    float* __restrict__ O, float* __restrict__ L)
{
  const int qt = blockIdx.x, h = blockIdx.y, kc = blockIdx.z;
  const int n0 = qt * 64;
  __shared__ u16 Qs[64][32];
  __shared__ u16 Ks[128][32];
  __shared__ u16 Vt[32][128];
  __shared__ u16 Ps[64][128];
  const int tid = threadIdx.x;
  const int wv = tid >> 6, l = tid & 63;
  const int lr = l & 15, lq = l >> 4;
  const int sr = tid >> 2, sb = tid & 3;
  const int kr = tid >> 1, kb = tid & 1;
  const int vr = tid >> 3, vb = tid & 7;
  *(bf16x8*)&Qs[sr][(sb ^ (sr & 3)) * 8] =
      *(const bf16x8*)(qk + (size_t)(n0 + sr) * 256 + h * 32 + sb * 8);
  __syncthreads();
  const float sc = 0.17677669529663687f;  // 1/sqrt(32), folded into Q frag
  bf16x8 qf;
  {
    bf16x8 qraw = *(const bf16x8*)&Qs[16 * wv + lr][(lq ^ (lr & 3)) * 8];
#pragma unroll
    for (int t = 0; t < 8; t++)
      qf[t] = (short)f2b(b2f((u16)qraw[t]) * sc);
  }
  f32x4 o0 = {}, o1 = {};
  float psum[4] = {0.f, 0.f, 0.f, 0.f};
  for (int t = 0; t < 8; t++) {
    const int m0 = kc * 1024 + t * 128;
    __syncthreads();
#pragma unroll
    for (int cc = 0; cc < 2; cc++) {
      int ch = kb + 2 * cc;
      *(bf16x8*)&Ks[kr][(ch ^ (kr & 3)) * 8] =
          *(const bf16x8*)(qk + (size_t)(m0 + kr) * 256 + 128 + h * 32 + ch * 8);
    }
#pragma unroll
    for (int cc = 0; cc < 2; cc++) {
      int ch = vb + 8 * cc;
      *(bf16x8*)&Vt[vr][(ch ^ (vr & 15)) * 8] =
          *(const bf16x8*)(Vg + (size_t)(h * 32 + vr) * 4096 + m0 + ch * 8);
    }
    __syncthreads();
    f32x4 s[8];
#pragma unroll
    for (int jt = 0; jt < 8; jt++) {
      bf16x8 kf = *(const bf16x8*)&Ks[16 * jt + lr][(lq ^ (lr & 3)) * 8];
      f32x4 z = {};
      s[jt] = __builtin_amdgcn_mfma_f32_16x16x32_bf16(qf, kf, z, 0, 0, 0);
    }
#pragma unroll
    for (int jt = 0; jt < 8; jt++)
#pragma unroll
      for (int r = 0; r < 4; r++) {
        float p = __expf(s[jt][r]);
        psum[r] += p;
        int qrow = 16 * wv + lq * 4 + r;
        int ch = 2 * jt + (lr >> 3);
        Ps[qrow][(ch ^ (qrow & 15)) * 8 + (lr & 7)] = f2b(p);
      }
    __syncthreads();
#pragma unroll
    for (int kk = 0; kk < 4; kk++) {
      int prow = 16 * wv + lr;
      bf16x8 pf = *(const bf16x8*)&Ps[prow][((4 * kk + lq) ^ (lr & 15)) * 8];
      bf16x8 v0 = *(const bf16x8*)&Vt[lr][((4 * kk + lq) ^ (lr & 15)) * 8];
      bf16x8 v1 = *(const bf16x8*)&Vt[16 + lr][((4 * kk + lq) ^ (lr & 15)) * 8];
      o0 = __builtin_amdgcn_mfma_f32_16x16x32_bf16(pf, v0, o0, 0, 0, 0);
      o1 = __builtin_amdgcn_mfma_f32_16x16x32_bf16(pf, v1, o1, 0, 0, 0);
    }
  }
#pragma unroll
  for (int r = 0; r < 4; r++) {
    int row = n0 + 16 * wv + lq * 4 + r;
    atomicAdd(&O[(size_t)row * 128 + h * 32 + lr],      o0[r]);
    atomicAdd(&O[(size_t)row * 128 + h * 32 + 16 + lr], o1[r]);
    float ps = psum[r];
    ps += __shfl_xor(ps, 1); ps += __shfl_xor(ps, 2);
    ps += __shfl_xor(ps, 4); ps += __shfl_xor(ps, 8);
    if (lr == 0) atomicAdd(&L[h * 4096 + row], ps);
  }
}

// ------- LayerNorm(A + R (+ rbias[col]))*g + b (proven r9) -----------------
__global__ __launch_bounds__(256) void ln_res(
    const void* __restrict__ A, int a_mode, const float* __restrict__ R,
    const void* __restrict__ rbias,
    const void* __restrict__ g, const void* __restrict__ b,
    u16* __restrict__ out_bf, float* __restrict__ out_f32,
    const int* __restrict__ dflag)
{
  const int wbf = *dflag;
  const int abf = a_mode ? wbf : 0;
  int row = blockIdx.x * 4 + (threadIdx.x >> 6);
  int lane = threadIdx.x & 63;
  size_t i0 = (size_t)row * 128 + lane, i1 = i0 + 64;
  float v0 = ld1(A, i0, abf) + R[i0];
  float v1 = ld1(A, i1, abf) + R[i1];
  if (rbias) { v0 += ld1(rbias, lane, wbf); v1 += ld1(rbias, lane + 64, wbf); }
  float s = v0 + v1, sq = v0 * v0 + v1 * v1;
  for (int off = 32; off; off >>= 1) { s += __shfl_down(s, off); sq += __shfl_down(sq, off); }
  s = __shfl(s, 0); sq = __shfl(sq, 0);
  float mu = s * (1.f / 128.f);
  float var = sq * (1.f / 128.f) - mu * mu;
  float rs = rsqrtf(var + 1e-5f);
  float r0 = (v0 - mu) * rs * ld1(g, lane, wbf) + ld1(b, lane, wbf);
  float r1 = (v1 - mu) * rs * ld1(g, lane + 64, wbf) + ld1(b, lane + 64, wbf);
  out_bf[i0] = f2b(r0);
  out_bf[i1] = f2b(r1);
  if (out_f32) { out_f32[i0] = r0; out_f32[i1] = r1; }
}

// ---------------- scan + dinv + cursor-zero (proven r9) --------------------
__global__ __launch_bounds__(1024) void scan4096(
    const int* __restrict__ counts, int* __restrict__ offs,
    float* __restrict__ dinv)
{
  __shared__ int buf[4096];
  __shared__ int part[1024];
  int t = threadIdx.x;
  for (int i = t; i < 4096; i += 1024) buf[i] = counts[i];
  __syncthreads();
  int base = t * 4;
  int s = buf[base] + buf[base + 1] + buf[base + 2] + buf[base + 3];
  part[t] = s;
  __syncthreads();
  for (int off = 1; off < 1024; off <<= 1) {
    int v = (t >= off) ? part[t - off] : 0;
    __syncthreads();
    part[t] += v;
    __syncthreads();
  }
  int run = (t == 0) ? 0 : part[t - 1];
  for (int j = 0; j < 4; j++) {
    int c = buf[base + j];
    offs[base + j] = run;
    dinv[base + j] = rsqrtf((float)(c + 1));
    run += c;
  }
  if (t == 1023) offs[4096] = run;
}

// -------- GCN gather, ushort4-vectorized (proven r9) -----------------------
__global__ __launch_bounds__(256) void gcn_gather(
    const u16* __restrict__ h, const float* __restrict__ dinv,
    const int* __restrict__ offs, const int* __restrict__ csr,
    const void* __restrict__ bias, void* __restrict__ out,
    int F, int relu, int final_out, const int* __restrict__ dflag)
{
  const int wbf = *dflag;
  const int tpn = F >> 2;
  const int node = blockIdx.x * (256 / tpn) + threadIdx.x / tpn;
  const int f = (threadIdx.x % tpn) * 4;
  float di = dinv[node];
  ushort4 hv = *(const ushort4*)(h + (size_t)node * F + f);
  float a0 = di * b2f(hv.x), a1 = di * b2f(hv.y);
  float a2 = di * b2f(hv.z), a3 = di * b2f(hv.w);
  int e0 = offs[node], e1 = offs[node + 1];
  for (int e = e0; e < e1; e++) {
    int s = csr[e];
    float ds = dinv[s];
    ushort4 sv = *(const ushort4*)(h + (size_t)s * F + f);
    a0 += ds * b2f(sv.x); a1 += ds * b2f(sv.y);
    a2 += ds * b2f(sv.z); a3 += ds * b2f(sv.w);
  }
  float b0 = bias ? ld1(bias, f, wbf)     : 0.f;
  float b1 = bias ? ld1(bias, f + 1, wbf) : 0.f;
  float b2 = bias ? ld1(bias, f + 2, wbf) : 0.f;
  float b3 = bias ? ld1(bias, f + 3, wbf) : 0.f;
  float v0 = a0 * di + b0, v1 = a1 * di + b1;
  float v2 = a2 * di + b2, v3 = a3 * di + b3;
  if (relu) {
    v0 = fmaxf(v0, 0.f); v1 = fmaxf(v1, 0.f);
    v2 = fmaxf(v2, 0.f); v3 = fmaxf(v3, 0.f);
  }
  size_t idx = (size_t)node * F + f;
  if (!final_out || wbf) {
    *(ushort4*)((u16*)out + idx) = make_ushort4(f2b(v0), f2b(v1), f2b(v2), f2b(v3));
  } else {
    *(float4*)((float*)out + idx) = make_float4(v0, v1, v2, v3);
  }
}

extern "C" void kernel_launch(void* const* d_in, const int* in_sizes, int n_in,
                              void* d_out, int out_size, void* d_ws, size_t ws_size,
                              hipStream_t stream)
{
  const void* x          = d_in[0];
  const int*  edge       = (const int*)d_in[1];
  const void* in_proj_w  = d_in[2];
  const void* in_proj_b  = d_in[3];
  const void* out_proj_w = d_in[4];
  const void* out_proj_b = d_in[5];
  const void* ln1_g      = d_in[6];
  const void* ln1_b      = d_in[7];
  const void* ffn_w1     = d_in[8];
  const void* ffn_b1     = d_in[9];
  const void* ffn_w2     = d_in[10];
  const void* ffn_b2     = d_in[11];
  const void* ln2_g      = d_in[12];
  const void* ln2_b      = d_in[13];
  const void* g1w        = d_in[14];
  const void* g1b        = d_in[15];
  const void* g2w        = d_in[16];
  const void* g2b        = d_in[17];
  const void* g3w        = d_in[18];
  const void* g3b        = d_in[19];
  const int E = in_sizes[1] / 2;
  const int* esrc = edge;
  const int* edst = edge + E;

  char* wsb     = (char*)d_ws;
  // disjoint layout; [3145728, 7438336) is the single zero region
  u16*   qkQK   = (u16*)(wsb + 0);          // 2 MB
  u16*   Vg     = (u16*)(wsb + 2097152);    // 1 MB
  float* Oacc   = (float*)(wsb + 3145728);  // 2 MB
  float* Lacc   = (float*)(wsb + 5242880);  // 64 KB
  float* ff2    = (float*)(wsb + 5308416);  // 2 MB
  int*   counts = (int*)(wsb + 7405568);    // 16 KB
  int*   cursor = (int*)(wsb + 7421952);    // 16 KB  (zero region ends 7438336)
  int*   offs   = (int*)(wsb + 7438336);
  int*   csr    = (int*)(wsb + 7454724);
  float* dinv   = (float*)(wsb + 7979012);
  int*   dflag  = (int*)(wsb + 7995396);
  float* y_f32  = (float*)(wsb + 8388608);  // 2 MB
  u16*   y_bf   = (u16*)(wsb + 10485760);   // 1 MB
  float* ao     = (float*)(wsb + 11534336); // 2 MB
  u16*   z_bf   = (u16*)(wsb + 13631488);   // 1 MB
  u16*   az     = (u16*)(wsb + 14680064);   // 1 MB
  u16*   h1     = (u16*)(wsb + 15728640);   // 2 MB
  u16*   ah1    = (u16*)(wsb + 17825792);   // 2 MB
  u16*   h2     = (u16*)(wsb + 19922944);   // 2 MB
  u16*   t3     = (u16*)(wsb + 22020096);   // 512 KB
  u16*   ff1    = (u16*)(wsb + 23068672);   // 16 MB [4096][2048]

  // one memset: Oacc + Lacc + ff2 + counts + cursor
  hipMemsetAsync(wsb + 3145728, 0, 4292608, stream);
  // dtype detect (block 0) + degree count (blocks 1..512)
  det_count<<<513, 256, 0, stream>>>(x, dflag, edst, counts, E);
  scan4096<<<1, 1024, 0, stream>>>(counts, offs, dinv);
  // fill_csr (512 blocks) overlapped with in_proj GEMM (384 blocks)
  csr_inproj<<<896, 256, 0, stream>>>(x, in_proj_w, in_proj_b, qkQK, Vg, dflag,
      esrc, edst, offs, cursor, csr, E);

  attn_part<<<dim3(64, 4, 4), 256, 0, stream>>>(qkQK, Vg, Oacc, Lacc);
  gemm_mfma<<<dim3(2, 64), 256, 0, stream>>>(Oacc, out_proj_w, out_proj_b, ao, nullptr,
      128, 128, 128, 128, 0, 0, /*f32out+bias+Af32*/ 4 | 8 | 64, dflag, Lacc);
  ln_res<<<1024, 256, 0, stream>>>(x, 1, ao, nullptr, ln1_g, ln1_b, y_bf, y_f32, dflag);
  // FFN: one w1 call (N=2048), then z=8 K-split atomic w2 (1024 blocks);
  // ffn_b2 applied in ln2's rbias (atomic path would add it 8x)
  gemm_mfma<<<dim3(32, 64), 256, 0, stream>>>(y_bf, ffn_w1, ffn_b1, ff1, nullptr,
      2048, 128, 128, 128, 0, 0, /*relu+bias*/ 1 | 8, dflag, nullptr);
  gemm_mfma<<<dim3(2, 64, 8), 256, 0, stream>>>(ff1, ffn_w2, nullptr, ff2, nullptr,
      128, 2048, 2048, 2048, 0, 0, /*f32 atomic*/ 4 | 32, dflag, nullptr);
  ln_res<<<1024, 256, 0, stream>>>(y_f32, 0, ff2, ffn_b2, ln2_g, ln2_b, z_bf, nullptr, dflag);

  // 3-layer GCN; aggregation commutes with the weight multiply
  gcn_gather<<<512, 256, 0, stream>>>(z_bf, dinv, offs, csr, nullptr, az, 128, 0, 0, dflag);
  gemm_mfma<<<dim3(4, 64), 256, 0, stream>>>(az, g1w, g1b, h1, nullptr,
      256, 128, 128, 128, 0, 0, /*relu+bias*/ 1 | 8, dflag, nullptr);
  gcn_gather<<<1024, 256, 0, stream>>>(h1, dinv, offs, csr, nullptr, ah1, 256, 0, 0, dflag);
  gemm_mfma<<<dim3(4, 64), 256, 0, stream>>>(ah1, g2w, g2b, h2, nullptr,
      256, 256, 256, 256, 0, 0, /*relu+bias*/ 1 | 8, dflag, nullptr);
  gemm_mfma<<<dim3(1, 64), 256, 0, stream>>>(h2, g3w, nullptr, t3, nullptr,
      64, 256, 256, 256, 0, 0, 0, dflag, nullptr);
  gcn_gather<<<256, 256, 0, stream>>>(t3, dinv, offs, csr, g3b, d_out, 64, 0, 1, dflag);
}